// Round 4
// baseline (218.629 us; speedup 1.0000x reference)
//
#include <hip/hip_runtime.h>
#include <cstdint>
#include <cstddef>

#define TPB 256
#define LPAD 136   // shorts per LDS row (272 B, 16B-aligned stride)

using frag_ab = __attribute__((ext_vector_type(8))) short;  // 8 bf16
using f32x4   = __attribute__((ext_vector_type(4))) float;  // 4 fp32 acc
using u16x4   = __attribute__((ext_vector_type(4))) ushort; // 4 bf16 (8B)

__device__ inline ushort f2b(float f) {
    uint u = __builtin_bit_cast(uint, f);
    u = (u + 0x7FFFu + ((u >> 16) & 1u)) >> 16;
    return (ushort)u;
}
__device__ inline float b2f_lo(uint u) { return __builtin_bit_cast(float, u << 16); }
__device__ inline float b2f_hi(uint u) { return __builtin_bit_cast(float, u & 0xFFFF0000u); }

// ---------------------------------------------------------------------------
// pack: fp32 [128][128] weight -> bf16 fragment order (used as A-operand of
// swapped product: A[m=feat][k] = W[k][feat]).
// frag idx = ((ntile*4 + kstep)*64 + lane)*8 + j
// element  = W[rowoff + kstep*32 + (lane>>4)*8 + j][ntile*16 + (lane&15)]
// ---------------------------------------------------------------------------
__global__ __launch_bounds__(TPB) void pack_kernel(
    const float* __restrict__ h_w1, const float* __restrict__ f_w,
    const float* __restrict__ g_w1, const float* __restrict__ g_w2,
    short* __restrict__ W1pk, short* __restrict__ Wfpk,
    short* __restrict__ G1pk, short* __restrict__ G2pk)
{
    int m   = blockIdx.y;
    int fid = blockIdx.x * TPB + threadIdx.x;     // 0..2047
    int lane = fid & 63, ks = (fid >> 6) & 3, nt = fid >> 8;
    const float* src; short* dst; int rowoff = 0;
    if      (m == 0) { src = h_w1; dst = W1pk; }
    else if (m == 1) { src = f_w;  dst = Wfpk; rowoff = 3; }
    else if (m == 2) { src = g_w1; dst = G1pk; }
    else             { src = g_w2; dst = G2pk; }
    int col   = nt * 16 + (lane & 15);
    int kbase = ks * 32 + ((lane >> 4) << 3);
    frag_ab f;
#pragma unroll
    for (int j = 0; j < 8; ++j)
        f[j] = (short)f2b(src[(size_t)(rowoff + kbase + j) * 128 + col]);
    *(frag_ab*)(dst + (((size_t)(nt * 4 + ks) * 64 + lane) << 3)) = f;
}

// ---------------------------------------------------------------------------
// prehist: per-node phase (no LDS, swapped MFMA) + edge histogram chunk.
//   lane owns node = blk*64 + wave*16 + (lane&15); kg = lane>>4 picks k-chunk.
//   D[feat][node]: lane holds feats nt*16+kg*4+j for its node.
// ---------------------------------------------------------------------------
__global__ __launch_bounds__(TPB) void prehist_kernel(
    const float* __restrict__ x, const float* __restrict__ pos,
    const short* __restrict__ W1pk, const float* __restrict__ h_b1,
    const float* __restrict__ h_w2, const float* __restrict__ h_b2,
    const short* __restrict__ Wfpk, const float* __restrict__ f_w,
    const float* __restrict__ f_b,
    ushort* __restrict__ A2h, ushort* __restrict__ Bvh,
    const int* __restrict__ ei, int* __restrict__ counts,
    int M, int E, int echunk)
{
    const int tid  = threadIdx.x;
    const int lane = tid & 63;
    const int wave = tid >> 6;
    const int kg   = lane >> 4;
    const int node = blockIdx.x * 64 + wave * 16 + (lane & 15);
    const int nc   = node < M ? node : M - 1;

    // B-fragments of x^T: lane loads 8 contiguous fp32 of its node's row
    frag_ab xb[4];
#pragma unroll
    for (int ks = 0; ks < 4; ++ks) {
        const float* px = x + (size_t)nc * 128 + ks * 32 + kg * 8;
        float4 v0 = *(const float4*)px;
        float4 v1 = *(const float4*)(px + 4);
        frag_ab f;
        f[0] = (short)f2b(v0.x); f[1] = (short)f2b(v0.y);
        f[2] = (short)f2b(v0.z); f[3] = (short)f2b(v0.w);
        f[4] = (short)f2b(v1.x); f[5] = (short)f2b(v1.y);
        f[6] = (short)f2b(v1.z); f[7] = (short)f2b(v1.w);
        xb[ks] = f;
    }

    f32x4 acch[8], acca[8];
#pragma unroll
    for (int nt = 0; nt < 8; ++nt) { acch[nt] = (f32x4)0.f; acca[nt] = (f32x4)0.f; }
#pragma unroll
    for (int ks = 0; ks < 4; ++ks) {
#pragma unroll
        for (int nt = 0; nt < 8; ++nt) {
            frag_ab wh = *(const frag_ab*)(W1pk + (((nt * 4 + ks) * 64 + lane) << 3));
            acch[nt] = __builtin_amdgcn_mfma_f32_16x16x32_bf16(wh, xb[ks], acch[nt], 0, 0, 0);
            frag_ab wf = *(const frag_ab*)(Wfpk + (((nt * 4 + ks) * 64 + lane) << 3));
            acca[nt] = __builtin_amdgcn_mfma_f32_16x16x32_bf16(wf, xb[ks], acca[nt], 0, 0, 0);
        }
    }

    // delta head: partial dot over this lane's 32 feats, reduce over kg groups
    float d0 = 0.f, d1 = 0.f, d2 = 0.f;
#pragma unroll
    for (int nt = 0; nt < 8; ++nt) {
        int f0 = nt * 16 + kg * 4;
        float4 b1 = *(const float4*)(h_b1 + f0);
        float w2[12];
        *(float4*)(w2 + 0) = *(const float4*)(h_w2 + f0 * 3);
        *(float4*)(w2 + 4) = *(const float4*)(h_w2 + f0 * 3 + 4);
        *(float4*)(w2 + 8) = *(const float4*)(h_w2 + f0 * 3 + 8);
#pragma unroll
        for (int j = 0; j < 4; ++j) {
            float h = fmaxf(acch[nt][j] + ((const float*)&b1)[j], 0.f);
            d0 += h * w2[j * 3 + 0];
            d1 += h * w2[j * 3 + 1];
            d2 += h * w2[j * 3 + 2];
        }
    }
    d0 += __shfl_xor(d0, 16); d0 += __shfl_xor(d0, 32);
    d1 += __shfl_xor(d1, 16); d1 += __shfl_xor(d1, 32);
    d2 += __shfl_xor(d2, 16); d2 += __shfl_xor(d2, 32);
    d0 = tanhf(d0 + h_b2[0]);
    d1 = tanhf(d1 + h_b2[1]);
    d2 = tanhf(d2 + h_b2[2]);

    float p0 = pos[(size_t)nc * 3 + 0];
    float p1 = pos[(size_t)nc * 3 + 1];
    float p2 = pos[(size_t)nc * 3 + 2];

    if (node < M) {
#pragma unroll
        for (int nt = 0; nt < 8; ++nt) {
            int f0 = nt * 16 + kg * 4;
            float4 w0 = *(const float4*)(f_w + f0);
            float4 w1 = *(const float4*)(f_w + 128 + f0);
            float4 w2 = *(const float4*)(f_w + 256 + f0);
            float4 fb = *(const float4*)(f_b + f0);
            u16x4 av, bv;
#pragma unroll
            for (int j = 0; j < 4; ++j) {
                float ww0 = ((const float*)&w0)[j];
                float ww1 = ((const float*)&w1)[j];
                float ww2 = ((const float*)&w2)[j];
                float pw = p0 * ww0 + p1 * ww1 + p2 * ww2;
                float dw = d0 * ww0 + d1 * ww1 + d2 * ww2;
                av[j] = f2b(acca[nt][j] + pw);
                bv[j] = f2b(((const float*)&fb)[j] + dw - pw);
            }
            *(u16x4*)(A2h + (size_t)node * 128 + f0) = av;
            *(u16x4*)(Bvh + (size_t)node * 128 + f0) = bv;
        }
    }

    // histogram chunk (independent work, hides tail)
    int base = blockIdx.x * echunk;
    int end  = base + echunk; if (end > E) end = E;
    for (int i = base + tid; i < end; i += TPB)
        atomicAdd(&counts[ei[E + i]], 1);
}

// ---------------------------------------------------------------------------
// hierarchical exclusive scan of counts -> offs, cursor
// ---------------------------------------------------------------------------
__global__ __launch_bounds__(TPB) void scan1_kernel(
    const int* __restrict__ counts, int* __restrict__ partial)
{
    int tid = threadIdx.x;
    int4 v = *(const int4*)(counts + (size_t)blockIdx.x * 1024 + tid * 4);
    int s = v.x + v.y + v.z + v.w;
#pragma unroll
    for (int m = 1; m < 64; m <<= 1) s += __shfl_xor(s, m);
    __shared__ int ws[4];
    if ((tid & 63) == 0) ws[tid >> 6] = s;
    __syncthreads();
    if (tid == 0) partial[blockIdx.x] = ws[0] + ws[1] + ws[2] + ws[3];
}

__global__ __launch_bounds__(64) void scan2_kernel(
    int* __restrict__ partial, int* __restrict__ offs, int nblk, int M)
{
    int tid = threadIdx.x;
    int v = (tid < nblk) ? partial[tid] : 0;
    int s = v;
#pragma unroll
    for (int d = 1; d < 64; d <<= 1) {
        int t = __shfl_up(s, d);
        if (tid >= d) s += t;
    }
    if (tid < nblk) partial[tid] = s - v;   // exclusive
    if (tid == 63) offs[M] = s;             // total = E
}

__global__ __launch_bounds__(TPB) void scan3_kernel(
    const int* __restrict__ counts, const int* __restrict__ partial,
    int* __restrict__ offs, int* __restrict__ cursor, int M)
{
    int tid = threadIdx.x;
    int base = blockIdx.x * 1024 + tid * 4;
    int4 v = *(const int4*)(counts + base);
    int s = v.x + v.y + v.z + v.w;
    int incl = s;
#pragma unroll
    for (int d = 1; d < 64; d <<= 1) {
        int t = __shfl_up(incl, d);
        if ((tid & 63) >= d) incl += t;
    }
    __shared__ int ws[4];
    if ((tid & 63) == 63) ws[tid >> 6] = incl;
    __syncthreads();
    int wp = 0;
#pragma unroll
    for (int w = 0; w < 4; ++w) wp += (w < (tid >> 6)) ? ws[w] : 0;
    int run = partial[blockIdx.x] + wp + incl - s;
    int vv[4] = {v.x, v.y, v.z, v.w};
#pragma unroll
    for (int i = 0; i < 4; ++i) {
        if (base + i < M) { offs[base + i] = run; cursor[base + i] = run; }
        run += vv[i];
    }
}

__global__ __launch_bounds__(TPB) void scatter_kernel(
    const int* __restrict__ ei, int* __restrict__ cursor,
    int* __restrict__ ssrc, int E)
{
    int e = blockIdx.x * TPB + threadIdx.x;
    if (e >= E) return;
    int d = ei[E + e];
    int p = atomicAdd(&cursor[d], 1);
    ssrc[p] = ei[e];
}

// ---------------------------------------------------------------------------
// redpost: fused segmented-reduce + node-update MLP.
//   phase 1: wave reduces its 16 rows (lane owns 2 cols), bf16 -> wave-private
//            LDS in transposed [node][k] layout (stride LPAD, 16B-aligned).
//   phase 2: hidden2^T = relu(G1t·aggrT + b) via swapped MFMA, back to LDS.
//   phase 3: out^T = G2t·hidden2T; epilogue adds g_b2 + x, fp32 stores.
//   All LDS is wave-private: no __syncthreads anywhere.
// ---------------------------------------------------------------------------
__global__ __launch_bounds__(TPB) void redpost_kernel(
    const float* __restrict__ x,
    const int* __restrict__ offs, const int* __restrict__ ssrc,
    const ushort* __restrict__ A2h, const ushort* __restrict__ Bvh,
    const short* __restrict__ G1pk, const float* __restrict__ g_b1,
    const short* __restrict__ G2pk, const float* __restrict__ g_b2,
    float* __restrict__ out, int M)
{
    __shared__ short lds[4 * 16 * LPAD];
    const int tid  = threadIdx.x;
    const int lane = tid & 63;
    const int wave = tid >> 6;
    const int kg   = lane >> 4;
    short* ws = lds + wave * 16 * LPAD;

    const int row0 = blockIdx.x * 64 + wave * 16;
    const int c = lane * 2;

    // phase 1: segmented reduce, 16 rows sequential, unroll-4 gather
    for (int r = 0; r < 16; ++r) {
        int row = row0 + r;
        float a0 = 0.f, a1 = 0.f;
        if (row < M) {
            uint bu = *(const uint*)(Bvh + (size_t)row * 128 + c);
            float b0 = b2f_lo(bu), b1 = b2f_hi(bu);
            int k = offs[row], k1 = offs[row + 1];
            for (; k + 3 < k1; k += 4) {
                int s0 = ssrc[k], s1 = ssrc[k + 1];
                int s2 = ssrc[k + 2], s3 = ssrc[k + 3];
                uint u0 = *(const uint*)(A2h + (size_t)s0 * 128 + c);
                uint u1 = *(const uint*)(A2h + (size_t)s1 * 128 + c);
                uint u2 = *(const uint*)(A2h + (size_t)s2 * 128 + c);
                uint u3 = *(const uint*)(A2h + (size_t)s3 * 128 + c);
                a0 += fmaxf(b2f_lo(u0) + b0, 0.f) + fmaxf(b2f_lo(u1) + b0, 0.f)
                    + fmaxf(b2f_lo(u2) + b0, 0.f) + fmaxf(b2f_lo(u3) + b0, 0.f);
                a1 += fmaxf(b2f_hi(u0) + b1, 0.f) + fmaxf(b2f_hi(u1) + b1, 0.f)
                    + fmaxf(b2f_hi(u2) + b1, 0.f) + fmaxf(b2f_hi(u3) + b1, 0.f);
            }
            for (; k < k1; ++k) {
                uint u0 = *(const uint*)(A2h + (size_t)ssrc[k] * 128 + c);
                a0 += fmaxf(b2f_lo(u0) + b0, 0.f);
                a1 += fmaxf(b2f_hi(u0) + b1, 0.f);
            }
        }
        uint packed = (uint)f2b(a0) | ((uint)f2b(a1) << 16);
        *(uint*)(ws + r * LPAD + c) = packed;
    }
    // wave-private LDS, in-order DS pipe: no barrier needed

    // phase 2: GEMM1 (swapped): hidden2^T
    f32x4 h2[8];
#pragma unroll
    for (int nt = 0; nt < 8; ++nt) h2[nt] = (f32x4)0.f;
#pragma unroll
    for (int ks = 0; ks < 4; ++ks) {
        frag_ab bfr = *(const frag_ab*)(ws + (lane & 15) * LPAD + ks * 32 + kg * 8);
#pragma unroll
        for (int nt = 0; nt < 8; ++nt) {
            frag_ab g = *(const frag_ab*)(G1pk + (((nt * 4 + ks) * 64 + lane) << 3));
            h2[nt] = __builtin_amdgcn_mfma_f32_16x16x32_bf16(g, bfr, h2[nt], 0, 0, 0);
        }
    }
    // relu+bias -> bf16 -> overwrite LDS (reads above precede, in-order)
#pragma unroll
    for (int nt = 0; nt < 8; ++nt) {
        int f0 = nt * 16 + kg * 4;
        float4 gb = *(const float4*)(g_b1 + f0);
        u16x4 hv;
#pragma unroll
        for (int j = 0; j < 4; ++j)
            hv[j] = f2b(fmaxf(h2[nt][j] + ((const float*)&gb)[j], 0.f));
        *(u16x4*)(ws + (lane & 15) * LPAD + f0) = hv;
    }

    // phase 3: GEMM2 (swapped): out^T
    f32x4 o[8];
#pragma unroll
    for (int nt = 0; nt < 8; ++nt) o[nt] = (f32x4)0.f;
#pragma unroll
    for (int ks = 0; ks < 4; ++ks) {
        frag_ab bfr = *(const frag_ab*)(ws + (lane & 15) * LPAD + ks * 32 + kg * 8);
#pragma unroll
        for (int nt = 0; nt < 8; ++nt) {
            frag_ab g = *(const frag_ab*)(G2pk + (((nt * 4 + ks) * 64 + lane) << 3));
            o[nt] = __builtin_amdgcn_mfma_f32_16x16x32_bf16(g, bfr, o[nt], 0, 0, 0);
        }
    }

    int node = row0 + (lane & 15);
    if (node < M) {
#pragma unroll
        for (int nt = 0; nt < 8; ++nt) {
            int f0 = nt * 16 + kg * 4;
            float4 xv = *(const float4*)(x + (size_t)node * 128 + f0);
            float4 gb = *(const float4*)(g_b2 + f0);
            float4 ov;
            ov.x = o[nt][0] + gb.x + xv.x;
            ov.y = o[nt][1] + gb.y + xv.y;
            ov.z = o[nt][2] + gb.z + xv.z;
            ov.w = o[nt][3] + gb.w + xv.w;
            *(float4*)(out + (size_t)node * 128 + f0) = ov;
        }
    }
}

extern "C" void kernel_launch(void* const* d_in, const int* in_sizes, int n_in,
                              void* d_out, int out_size, void* d_ws, size_t ws_size,
                              hipStream_t stream)
{
    const float* x    = (const float*)d_in[0];
    const float* pos  = (const float*)d_in[1];
    const int*   ei   = (const int*)d_in[2];
    const float* h_w1 = (const float*)d_in[3];
    const float* h_b1 = (const float*)d_in[4];
    const float* h_w2 = (const float*)d_in[5];
    const float* h_b2 = (const float*)d_in[6];
    const float* f_w  = (const float*)d_in[7];
    const float* f_b  = (const float*)d_in[8];
    const float* g_w1 = (const float*)d_in[9];
    const float* g_b1 = (const float*)d_in[10];
    const float* g_w2 = (const float*)d_in[11];
    const float* g_b2 = (const float*)d_in[12];

    const int M = in_sizes[1] / 3;       // 50000
    const int E = in_sizes[2] / 2;       // 600000
    const int nb = (M + 63) / 64;        // 782
    const int nblk = (M + 1023) / 1024;  // 49
    const int Mpad = nblk * 1024;
    const int echunk = (E + nb - 1) / nb;

    ushort* A2h  = (ushort*)d_ws;                          // [M][128] bf16
    ushort* Bvh  = A2h + (size_t)M * 128;                  // [M][128] bf16
    short* W1pk  = (short*)(Bvh + (size_t)M * 128);        // 16384 each
    short* Wfpk  = W1pk + 16384;
    short* G1pk  = Wfpk + 16384;
    short* G2pk  = G1pk + 16384;
    int* counts  = (int*)(G2pk + 16384);                   // [Mpad]
    int* partial = counts + Mpad;                          // [64]
    int* offs    = partial + 64;                           // [M+1]
    int* cursor  = offs + (M + 1);                         // [M]
    int* ssrc    = cursor + M;                             // [E]
    float* out   = (float*)d_out;

    hipMemsetAsync(counts, 0, (size_t)Mpad * sizeof(int), stream);
    pack_kernel<<<dim3(8, 4), TPB, 0, stream>>>(h_w1, f_w, g_w1, g_w2,
                                                W1pk, Wfpk, G1pk, G2pk);
    prehist_kernel<<<nb, TPB, 0, stream>>>(x, pos, W1pk, h_b1, h_w2, h_b2,
                                           Wfpk, f_w, f_b, A2h, Bvh,
                                           ei, counts, M, E, echunk);
    scan1_kernel<<<nblk, TPB, 0, stream>>>(counts, partial);
    scan2_kernel<<<1, 64, 0, stream>>>(partial, offs, nblk, M);
    scan3_kernel<<<nblk, TPB, 0, stream>>>(counts, partial, offs, cursor, M);
    scatter_kernel<<<(E + TPB - 1) / TPB, TPB, 0, stream>>>(ei, cursor, ssrc, E);
    redpost_kernel<<<nb, TPB, 0, stream>>>(x, offs, ssrc, A2h, Bvh,
                                           G1pk, g_b1, G2pk, g_b2, out, M);
}

// Round 5
// 178.380 us; speedup vs baseline: 1.2256x; 1.2256x over previous
//
#include <hip/hip_runtime.h>
#include <cstdint>
#include <cstddef>

#define TPB 256
#define LPAD 136   // shorts per LDS row (272 B, 16B-aligned stride)

using frag_ab = __attribute__((ext_vector_type(8))) short;  // 8 bf16
using f32x4   = __attribute__((ext_vector_type(4))) float;  // 4 fp32 acc
using u16x4   = __attribute__((ext_vector_type(4))) ushort; // 4 bf16 (8B)

__device__ inline ushort f2b(float f) {
    uint u = __builtin_bit_cast(uint, f);
    u = (u + 0x7FFFu + ((u >> 16) & 1u)) >> 16;
    return (ushort)u;
}
__device__ inline float b2f_lo(uint u) { return __builtin_bit_cast(float, u << 16); }
__device__ inline float b2f_hi(uint u) { return __builtin_bit_cast(float, u & 0xFFFF0000u); }

// ---------------------------------------------------------------------------
// pack: fp32 [128][128] weight -> bf16 fragment order (used as A-operand of
// swapped product: A[m=feat][k] = W[k][feat]).
// frag idx = ((ntile*4 + kstep)*64 + lane)*8 + j
// element  = W[rowoff + kstep*32 + (lane>>4)*8 + j][ntile*16 + (lane&15)]
// ---------------------------------------------------------------------------
__global__ __launch_bounds__(TPB) void pack_kernel(
    const float* __restrict__ h_w1, const float* __restrict__ f_w,
    const float* __restrict__ g_w1, const float* __restrict__ g_w2,
    short* __restrict__ W1pk, short* __restrict__ Wfpk,
    short* __restrict__ G1pk, short* __restrict__ G2pk)
{
    int m   = blockIdx.y;
    int fid = blockIdx.x * TPB + threadIdx.x;     // 0..2047
    int lane = fid & 63, ks = (fid >> 6) & 3, nt = fid >> 8;
    const float* src; short* dst; int rowoff = 0;
    if      (m == 0) { src = h_w1; dst = W1pk; }
    else if (m == 1) { src = f_w;  dst = Wfpk; rowoff = 3; }
    else if (m == 2) { src = g_w1; dst = G1pk; }
    else             { src = g_w2; dst = G2pk; }
    int col   = nt * 16 + (lane & 15);
    int kbase = ks * 32 + ((lane >> 4) << 3);
    frag_ab f;
#pragma unroll
    for (int j = 0; j < 8; ++j)
        f[j] = (short)f2b(src[(size_t)(rowoff + kbase + j) * 128 + col]);
    *(frag_ab*)(dst + (((size_t)(nt * 4 + ks) * 64 + lane) << 3)) = f;
}

// ---------------------------------------------------------------------------
// prehist: per-node phase (no LDS, swapped MFMA) + edge histogram chunk.
// ---------------------------------------------------------------------------
__global__ __launch_bounds__(TPB) void prehist_kernel(
    const float* __restrict__ x, const float* __restrict__ pos,
    const short* __restrict__ W1pk, const float* __restrict__ h_b1,
    const float* __restrict__ h_w2, const float* __restrict__ h_b2,
    const short* __restrict__ Wfpk, const float* __restrict__ f_w,
    const float* __restrict__ f_b,
    ushort* __restrict__ A2h, ushort* __restrict__ Bvh,
    const int* __restrict__ ei, int* __restrict__ counts,
    int M, int E, int echunk)
{
    const int tid  = threadIdx.x;
    const int lane = tid & 63;
    const int wave = tid >> 6;
    const int kg   = lane >> 4;
    const int node = blockIdx.x * 64 + wave * 16 + (lane & 15);
    const int nc   = node < M ? node : M - 1;

    // B-fragments of x^T: lane loads 8 contiguous fp32 of its node's row
    frag_ab xb[4];
#pragma unroll
    for (int ks = 0; ks < 4; ++ks) {
        const float* px = x + (size_t)nc * 128 + ks * 32 + kg * 8;
        float4 v0 = *(const float4*)px;
        float4 v1 = *(const float4*)(px + 4);
        frag_ab f;
        f[0] = (short)f2b(v0.x); f[1] = (short)f2b(v0.y);
        f[2] = (short)f2b(v0.z); f[3] = (short)f2b(v0.w);
        f[4] = (short)f2b(v1.x); f[5] = (short)f2b(v1.y);
        f[6] = (short)f2b(v1.z); f[7] = (short)f2b(v1.w);
        xb[ks] = f;
    }

    f32x4 acch[8], acca[8];
#pragma unroll
    for (int nt = 0; nt < 8; ++nt) { acch[nt] = (f32x4)0.f; acca[nt] = (f32x4)0.f; }
#pragma unroll
    for (int ks = 0; ks < 4; ++ks) {
#pragma unroll
        for (int nt = 0; nt < 8; ++nt) {
            frag_ab wh = *(const frag_ab*)(W1pk + (((nt * 4 + ks) * 64 + lane) << 3));
            acch[nt] = __builtin_amdgcn_mfma_f32_16x16x32_bf16(wh, xb[ks], acch[nt], 0, 0, 0);
            frag_ab wf = *(const frag_ab*)(Wfpk + (((nt * 4 + ks) * 64 + lane) << 3));
            acca[nt] = __builtin_amdgcn_mfma_f32_16x16x32_bf16(wf, xb[ks], acca[nt], 0, 0, 0);
        }
    }

    // delta head: partial dot over this lane's 32 feats, reduce over kg groups
    float d0 = 0.f, d1 = 0.f, d2 = 0.f;
#pragma unroll
    for (int nt = 0; nt < 8; ++nt) {
        int f0 = nt * 16 + kg * 4;
        float4 b1 = *(const float4*)(h_b1 + f0);
        float w2[12];
        *(float4*)(w2 + 0) = *(const float4*)(h_w2 + f0 * 3);
        *(float4*)(w2 + 4) = *(const float4*)(h_w2 + f0 * 3 + 4);
        *(float4*)(w2 + 8) = *(const float4*)(h_w2 + f0 * 3 + 8);
#pragma unroll
        for (int j = 0; j < 4; ++j) {
            float h = fmaxf(acch[nt][j] + ((const float*)&b1)[j], 0.f);
            d0 += h * w2[j * 3 + 0];
            d1 += h * w2[j * 3 + 1];
            d2 += h * w2[j * 3 + 2];
        }
    }
    d0 += __shfl_xor(d0, 16); d0 += __shfl_xor(d0, 32);
    d1 += __shfl_xor(d1, 16); d1 += __shfl_xor(d1, 32);
    d2 += __shfl_xor(d2, 16); d2 += __shfl_xor(d2, 32);
    d0 = tanhf(d0 + h_b2[0]);
    d1 = tanhf(d1 + h_b2[1]);
    d2 = tanhf(d2 + h_b2[2]);

    float p0 = pos[(size_t)nc * 3 + 0];
    float p1 = pos[(size_t)nc * 3 + 1];
    float p2 = pos[(size_t)nc * 3 + 2];

    if (node < M) {
#pragma unroll
        for (int nt = 0; nt < 8; ++nt) {
            int f0 = nt * 16 + kg * 4;
            float4 w0 = *(const float4*)(f_w + f0);
            float4 w1 = *(const float4*)(f_w + 128 + f0);
            float4 w2 = *(const float4*)(f_w + 256 + f0);
            float4 fb = *(const float4*)(f_b + f0);
            u16x4 av, bv;
#pragma unroll
            for (int j = 0; j < 4; ++j) {
                float ww0 = ((const float*)&w0)[j];
                float ww1 = ((const float*)&w1)[j];
                float ww2 = ((const float*)&w2)[j];
                float pw = p0 * ww0 + p1 * ww1 + p2 * ww2;
                float dw = d0 * ww0 + d1 * ww1 + d2 * ww2;
                av[j] = f2b(acca[nt][j] + pw);
                bv[j] = f2b(((const float*)&fb)[j] + dw - pw);
            }
            *(u16x4*)(A2h + (size_t)node * 128 + f0) = av;
            *(u16x4*)(Bvh + (size_t)node * 128 + f0) = bv;
        }
    }

    // histogram chunk (independent work, hides tail)
    int base = blockIdx.x * echunk;
    int end  = base + echunk; if (end > E) end = E;
    for (int i = base + tid; i < end; i += TPB)
        atomicAdd(&counts[ei[E + i]], 1);
}

// ---------------------------------------------------------------------------
// hierarchical exclusive scan of counts -> offs, cursor
// ---------------------------------------------------------------------------
__global__ __launch_bounds__(TPB) void scan1_kernel(
    const int* __restrict__ counts, int* __restrict__ partial)
{
    int tid = threadIdx.x;
    int4 v = *(const int4*)(counts + (size_t)blockIdx.x * 1024 + tid * 4);
    int s = v.x + v.y + v.z + v.w;
#pragma unroll
    for (int m = 1; m < 64; m <<= 1) s += __shfl_xor(s, m);
    __shared__ int ws[4];
    if ((tid & 63) == 0) ws[tid >> 6] = s;
    __syncthreads();
    if (tid == 0) partial[blockIdx.x] = ws[0] + ws[1] + ws[2] + ws[3];
}

__global__ __launch_bounds__(64) void scan2_kernel(
    int* __restrict__ partial, int* __restrict__ offs, int nblk, int M)
{
    int tid = threadIdx.x;
    int v = (tid < nblk) ? partial[tid] : 0;
    int s = v;
#pragma unroll
    for (int d = 1; d < 64; d <<= 1) {
        int t = __shfl_up(s, d);
        if (tid >= d) s += t;
    }
    if (tid < nblk) partial[tid] = s - v;   // exclusive
    if (tid == 63) offs[M] = s;             // total = E
}

__global__ __launch_bounds__(TPB) void scan3_kernel(
    const int* __restrict__ counts, const int* __restrict__ partial,
    int* __restrict__ offs, int* __restrict__ cursor, int M)
{
    int tid = threadIdx.x;
    int base = blockIdx.x * 1024 + tid * 4;
    int4 v = *(const int4*)(counts + base);
    int s = v.x + v.y + v.z + v.w;
    int incl = s;
#pragma unroll
    for (int d = 1; d < 64; d <<= 1) {
        int t = __shfl_up(incl, d);
        if ((tid & 63) >= d) incl += t;
    }
    __shared__ int ws[4];
    if ((tid & 63) == 63) ws[tid >> 6] = incl;
    __syncthreads();
    int wp = 0;
#pragma unroll
    for (int w = 0; w < 4; ++w) wp += (w < (tid >> 6)) ? ws[w] : 0;
    int run = partial[blockIdx.x] + wp + incl - s;
    int vv[4] = {v.x, v.y, v.z, v.w};
#pragma unroll
    for (int i = 0; i < 4; ++i) {
        if (base + i < M) { offs[base + i] = run; cursor[base + i] = run; }
        run += vv[i];
    }
}

__global__ __launch_bounds__(TPB) void scatter_kernel(
    const int* __restrict__ ei, int* __restrict__ cursor,
    int* __restrict__ ssrc, int E)
{
    int e = blockIdx.x * TPB + threadIdx.x;
    if (e >= E) return;
    int d = ei[E + e];
    int p = atomicAdd(&cursor[d], 1);
    ssrc[p] = ei[e];
}

// ---------------------------------------------------------------------------
// segmented reduce: ONE WAVE PER ROW (max TLP for the latency-bound gather),
// lane owns 2 cols, unroll-4, bf16 output.
// ---------------------------------------------------------------------------
__global__ __launch_bounds__(TPB) void reduce_kernel(
    const int* __restrict__ offs, const int* __restrict__ ssrc,
    const ushort* __restrict__ A2h, const ushort* __restrict__ Bvh,
    ushort* __restrict__ aggr, int M)
{
    int row = blockIdx.x * 4 + (threadIdx.x >> 6);
    if (row >= M) return;
    int lane = threadIdx.x & 63;
    int c = lane * 2;
    uint bu = *(const uint*)(Bvh + (size_t)row * 128 + c);
    float b0 = b2f_lo(bu), b1 = b2f_hi(bu);
    float a0 = 0.f, a1 = 0.f;
    int k  = offs[row];
    int k1 = offs[row + 1];
    for (; k + 3 < k1; k += 4) {
        int s0 = ssrc[k], s1 = ssrc[k + 1];
        int s2 = ssrc[k + 2], s3 = ssrc[k + 3];
        uint u0 = *(const uint*)(A2h + (size_t)s0 * 128 + c);
        uint u1 = *(const uint*)(A2h + (size_t)s1 * 128 + c);
        uint u2 = *(const uint*)(A2h + (size_t)s2 * 128 + c);
        uint u3 = *(const uint*)(A2h + (size_t)s3 * 128 + c);
        a0 += fmaxf(b2f_lo(u0) + b0, 0.f) + fmaxf(b2f_lo(u1) + b0, 0.f)
            + fmaxf(b2f_lo(u2) + b0, 0.f) + fmaxf(b2f_lo(u3) + b0, 0.f);
        a1 += fmaxf(b2f_hi(u0) + b1, 0.f) + fmaxf(b2f_hi(u1) + b1, 0.f)
            + fmaxf(b2f_hi(u2) + b1, 0.f) + fmaxf(b2f_hi(u3) + b1, 0.f);
    }
    for (; k < k1; ++k) {
        uint u0 = *(const uint*)(A2h + (size_t)ssrc[k] * 128 + c);
        a0 += fmaxf(b2f_lo(u0) + b0, 0.f);
        a1 += fmaxf(b2f_hi(u0) + b1, 0.f);
    }
    *(uint*)(aggr + (size_t)row * 128 + c) = (uint)f2b(a0) | ((uint)f2b(a1) << 16);
}

// ---------------------------------------------------------------------------
// post: out = relu(aggr@g_w1+g_b1)@g_w2 + g_b2 + x  via swapped MFMA.
// B-fragments (aggr^T) load DIRECTLY from global bf16 — no staging LDS, no
// barrier. Only the hidden2 redistribution bounces through wave-private LDS.
// ---------------------------------------------------------------------------
__global__ __launch_bounds__(TPB) void post_kernel(
    const float* __restrict__ x, const ushort* __restrict__ aggr,
    const short* __restrict__ G1pk, const float* __restrict__ g_b1,
    const short* __restrict__ G2pk, const float* __restrict__ g_b2,
    float* __restrict__ out, int M)
{
    __shared__ short lds[4 * 16 * LPAD];
    const int tid  = threadIdx.x;
    const int lane = tid & 63;
    const int wave = tid >> 6;
    const int kg   = lane >> 4;
    short* ws = lds + wave * 16 * LPAD;

    const int node = blockIdx.x * 64 + wave * 16 + (lane & 15);
    const int nc   = node < M ? node : M - 1;

    // B-fragments of aggr^T: direct 16B global loads
    frag_ab ab[4];
#pragma unroll
    for (int ks = 0; ks < 4; ++ks)
        ab[ks] = *(const frag_ab*)(aggr + (size_t)nc * 128 + ks * 32 + kg * 8);

    // GEMM1: hidden2^T
    f32x4 h2[8];
#pragma unroll
    for (int nt = 0; nt < 8; ++nt) h2[nt] = (f32x4)0.f;
#pragma unroll
    for (int ks = 0; ks < 4; ++ks) {
#pragma unroll
        for (int nt = 0; nt < 8; ++nt) {
            frag_ab g = *(const frag_ab*)(G1pk + (((nt * 4 + ks) * 64 + lane) << 3));
            h2[nt] = __builtin_amdgcn_mfma_f32_16x16x32_bf16(g, ab[ks], h2[nt], 0, 0, 0);
        }
    }
    // relu+bias -> bf16 -> wave-private LDS (in-order DS pipe, no barrier)
#pragma unroll
    for (int nt = 0; nt < 8; ++nt) {
        int f0 = nt * 16 + kg * 4;
        float4 gb = *(const float4*)(g_b1 + f0);
        u16x4 hv;
#pragma unroll
        for (int j = 0; j < 4; ++j)
            hv[j] = f2b(fmaxf(h2[nt][j] + ((const float*)&gb)[j], 0.f));
        *(u16x4*)(ws + (lane & 15) * LPAD + f0) = hv;
    }

    // GEMM2: out^T
    f32x4 o[8];
#pragma unroll
    for (int nt = 0; nt < 8; ++nt) o[nt] = (f32x4)0.f;
#pragma unroll
    for (int ks = 0; ks < 4; ++ks) {
        frag_ab bfr = *(const frag_ab*)(ws + (lane & 15) * LPAD + ks * 32 + kg * 8);
#pragma unroll
        for (int nt = 0; nt < 8; ++nt) {
            frag_ab g = *(const frag_ab*)(G2pk + (((nt * 4 + ks) * 64 + lane) << 3));
            o[nt] = __builtin_amdgcn_mfma_f32_16x16x32_bf16(g, bfr, o[nt], 0, 0, 0);
        }
    }

    if (node < M) {
#pragma unroll
        for (int nt = 0; nt < 8; ++nt) {
            int f0 = nt * 16 + kg * 4;
            float4 xv = *(const float4*)(x + (size_t)node * 128 + f0);
            float4 gb = *(const float4*)(g_b2 + f0);
            float4 ov;
            ov.x = o[nt][0] + gb.x + xv.x;
            ov.y = o[nt][1] + gb.y + xv.y;
            ov.z = o[nt][2] + gb.z + xv.z;
            ov.w = o[nt][3] + gb.w + xv.w;
            *(float4*)(out + (size_t)node * 128 + f0) = ov;
        }
    }
}

extern "C" void kernel_launch(void* const* d_in, const int* in_sizes, int n_in,
                              void* d_out, int out_size, void* d_ws, size_t ws_size,
                              hipStream_t stream)
{
    const float* x    = (const float*)d_in[0];
    const float* pos  = (const float*)d_in[1];
    const int*   ei   = (const int*)d_in[2];
    const float* h_w1 = (const float*)d_in[3];
    const float* h_b1 = (const float*)d_in[4];
    const float* h_w2 = (const float*)d_in[5];
    const float* h_b2 = (const float*)d_in[6];
    const float* f_w  = (const float*)d_in[7];
    const float* f_b  = (const float*)d_in[8];
    const float* g_w1 = (const float*)d_in[9];
    const float* g_b1 = (const float*)d_in[10];
    const float* g_w2 = (const float*)d_in[11];
    const float* g_b2 = (const float*)d_in[12];

    const int M = in_sizes[1] / 3;       // 50000
    const int E = in_sizes[2] / 2;       // 600000
    const int nb = (M + 63) / 64;        // 782
    const int nblk = (M + 1023) / 1024;  // 49
    const int Mpad = nblk * 1024;
    const int echunk = (E + nb - 1) / nb;

    ushort* A2h  = (ushort*)d_ws;                          // [M][128] bf16
    ushort* Bvh  = A2h + (size_t)M * 128;                  // [M][128] bf16
    ushort* aggr = Bvh + (size_t)M * 128;                  // [M][128] bf16
    short* W1pk  = (short*)(aggr + (size_t)M * 128);       // 16384 each
    short* Wfpk  = W1pk + 16384;
    short* G1pk  = Wfpk + 16384;
    short* G2pk  = G1pk + 16384;
    int* counts  = (int*)(G2pk + 16384);                   // [Mpad]
    int* partial = counts + Mpad;                          // [64]
    int* offs    = partial + 64;                           // [M+1]
    int* cursor  = offs + (M + 1);                         // [M]
    int* ssrc    = cursor + M;                             // [E]
    float* out   = (float*)d_out;

    hipMemsetAsync(counts, 0, (size_t)Mpad * sizeof(int), stream);
    pack_kernel<<<dim3(8, 4), TPB, 0, stream>>>(h_w1, f_w, g_w1, g_w2,
                                                W1pk, Wfpk, G1pk, G2pk);
    prehist_kernel<<<nb, TPB, 0, stream>>>(x, pos, W1pk, h_b1, h_w2, h_b2,
                                           Wfpk, f_w, f_b, A2h, Bvh,
                                           ei, counts, M, E, echunk);
    scan1_kernel<<<nblk, TPB, 0, stream>>>(counts, partial);
    scan2_kernel<<<1, 64, 0, stream>>>(partial, offs, nblk, M);
    scan3_kernel<<<nblk, TPB, 0, stream>>>(counts, partial, offs, cursor, M);
    scatter_kernel<<<(E + TPB - 1) / TPB, TPB, 0, stream>>>(ei, cursor, ssrc, E);
    reduce_kernel<<<(M + 3) / 4, TPB, 0, stream>>>(offs, ssrc, A2h, Bvh, aggr, M);
    post_kernel<<<nb, TPB, 0, stream>>>(x, aggr, G1pk, g_b1, G2pk, g_b2, out, M);
}

// Round 6
// 140.051 us; speedup vs baseline: 1.5611x; 1.2737x over previous
//
#include <hip/hip_runtime.h>
#include <cstdint>
#include <cstddef>

#define TPB 256
#define LPAD 136   // shorts per LDS row (272 B, 16B-aligned stride)

using frag_ab = __attribute__((ext_vector_type(8))) short;  // 8 bf16
using f32x4   = __attribute__((ext_vector_type(4))) float;  // 4 fp32 acc
using u16x4   = __attribute__((ext_vector_type(4))) ushort; // 4 bf16 (8B)

__device__ inline ushort f2b(float f) {
    uint u = __builtin_bit_cast(uint, f);
    u = (u + 0x7FFFu + ((u >> 16) & 1u)) >> 16;
    return (ushort)u;
}
__device__ inline float b2f_lo(uint u) { return __builtin_bit_cast(float, u << 16); }
__device__ inline float b2f_hi(uint u) { return __builtin_bit_cast(float, u & 0xFFFF0000u); }

// ---------------------------------------------------------------------------
// pack: fp32 [128][128] weight -> bf16 fragment order (used as A-operand of
// swapped product: A[m=feat][k] = W[k][feat]).
// frag idx = ((ntile*4 + kstep)*64 + lane)*8 + j
// element  = W[rowoff + kstep*32 + (lane>>4)*8 + j][ntile*16 + (lane&15)]
// ---------------------------------------------------------------------------
__global__ __launch_bounds__(TPB) void pack_kernel(
    const float* __restrict__ h_w1, const float* __restrict__ f_w,
    const float* __restrict__ g_w1, const float* __restrict__ g_w2,
    short* __restrict__ W1pk, short* __restrict__ Wfpk,
    short* __restrict__ G1pk, short* __restrict__ G2pk)
{
    int m   = blockIdx.y;
    int fid = blockIdx.x * TPB + threadIdx.x;     // 0..2047
    int lane = fid & 63, ks = (fid >> 6) & 3, nt = fid >> 8;
    const float* src; short* dst; int rowoff = 0;
    if      (m == 0) { src = h_w1; dst = W1pk; }
    else if (m == 1) { src = f_w;  dst = Wfpk; rowoff = 3; }
    else if (m == 2) { src = g_w1; dst = G1pk; }
    else             { src = g_w2; dst = G2pk; }
    int col   = nt * 16 + (lane & 15);
    int kbase = ks * 32 + ((lane >> 4) << 3);
    frag_ab f;
#pragma unroll
    for (int j = 0; j < 8; ++j)
        f[j] = (short)f2b(src[(size_t)(rowoff + kbase + j) * 128 + col]);
    *(frag_ab*)(dst + (((size_t)(nt * 4 + ks) * 64 + lane) << 3)) = f;
}

// ---------------------------------------------------------------------------
// prehist: per-node phase (swapped MFMA, weights staged in LDS) + histogram.
//   lane owns node = blk*64 + wave*16 + (lane&15); kg = lane>>4.
// ---------------------------------------------------------------------------
__global__ __launch_bounds__(TPB) void prehist_kernel(
    const float* __restrict__ x, const float* __restrict__ pos,
    const short* __restrict__ W1pk,   // Wfpk contiguous at +16384
    const float* __restrict__ h_b1,
    const float* __restrict__ h_w2, const float* __restrict__ h_b2,
    const float* __restrict__ f_w, const float* __restrict__ f_b,
    ushort* __restrict__ A2h, ushort* __restrict__ Bvh,
    const int* __restrict__ ei, int* __restrict__ counts,
    int M, int E, int echunk)
{
    __shared__ short wlds[32768];     // 64 KB: W1pk frag order, then Wfpk
    const int tid  = threadIdx.x;
    const int lane = tid & 63;
    const int wave = tid >> 6;
    const int kg   = lane >> 4;
    const int node = blockIdx.x * 64 + wave * 16 + (lane & 15);
    const int nc   = node < M ? node : M - 1;

    // issue x loads first (overlap with staging)
    float4 xv0[4], xv1[4];
#pragma unroll
    for (int ks = 0; ks < 4; ++ks) {
        const float* px = x + (size_t)nc * 128 + ks * 32 + kg * 8;
        xv0[ks] = *(const float4*)px;
        xv1[ks] = *(const float4*)(px + 4);
    }

    // stage both weight matrices (contiguous): 4096 int4s
#pragma unroll
    for (int i = 0; i < 16; ++i) {
        int id = i * TPB + tid;
        *(int4*)(wlds + (size_t)id * 8) = *(const int4*)(W1pk + (size_t)id * 8);
    }

    // convert x to bf16 fragments while staging lands
    frag_ab xb[4];
#pragma unroll
    for (int ks = 0; ks < 4; ++ks) {
        frag_ab f;
        f[0] = (short)f2b(xv0[ks].x); f[1] = (short)f2b(xv0[ks].y);
        f[2] = (short)f2b(xv0[ks].z); f[3] = (short)f2b(xv0[ks].w);
        f[4] = (short)f2b(xv1[ks].x); f[5] = (short)f2b(xv1[ks].y);
        f[6] = (short)f2b(xv1[ks].z); f[7] = (short)f2b(xv1[ks].w);
        xb[ks] = f;
    }
    __syncthreads();

    f32x4 acch[8], acca[8];
#pragma unroll
    for (int nt = 0; nt < 8; ++nt) { acch[nt] = (f32x4)0.f; acca[nt] = (f32x4)0.f; }
#pragma unroll
    for (int ks = 0; ks < 4; ++ks) {
#pragma unroll
        for (int nt = 0; nt < 8; ++nt) {
            frag_ab wh = *(const frag_ab*)(wlds + (((nt * 4 + ks) * 64 + lane) << 3));
            acch[nt] = __builtin_amdgcn_mfma_f32_16x16x32_bf16(wh, xb[ks], acch[nt], 0, 0, 0);
            frag_ab wf = *(const frag_ab*)(wlds + 16384 + (((nt * 4 + ks) * 64 + lane) << 3));
            acca[nt] = __builtin_amdgcn_mfma_f32_16x16x32_bf16(wf, xb[ks], acca[nt], 0, 0, 0);
        }
    }

    // delta head: partial dot over this lane's 32 feats, reduce over kg groups
    float d0 = 0.f, d1 = 0.f, d2 = 0.f;
#pragma unroll
    for (int nt = 0; nt < 8; ++nt) {
        int f0 = nt * 16 + kg * 4;
        float4 b1 = *(const float4*)(h_b1 + f0);
        float w2[12];
        *(float4*)(w2 + 0) = *(const float4*)(h_w2 + f0 * 3);
        *(float4*)(w2 + 4) = *(const float4*)(h_w2 + f0 * 3 + 4);
        *(float4*)(w2 + 8) = *(const float4*)(h_w2 + f0 * 3 + 8);
#pragma unroll
        for (int j = 0; j < 4; ++j) {
            float h = fmaxf(acch[nt][j] + ((const float*)&b1)[j], 0.f);
            d0 += h * w2[j * 3 + 0];
            d1 += h * w2[j * 3 + 1];
            d2 += h * w2[j * 3 + 2];
        }
    }
    d0 += __shfl_xor(d0, 16); d0 += __shfl_xor(d0, 32);
    d1 += __shfl_xor(d1, 16); d1 += __shfl_xor(d1, 32);
    d2 += __shfl_xor(d2, 16); d2 += __shfl_xor(d2, 32);
    d0 = tanhf(d0 + h_b2[0]);
    d1 = tanhf(d1 + h_b2[1]);
    d2 = tanhf(d2 + h_b2[2]);

    float p0 = pos[(size_t)nc * 3 + 0];
    float p1 = pos[(size_t)nc * 3 + 1];
    float p2 = pos[(size_t)nc * 3 + 2];

    if (node < M) {
#pragma unroll
        for (int nt = 0; nt < 8; ++nt) {
            int f0 = nt * 16 + kg * 4;
            float4 w0 = *(const float4*)(f_w + f0);
            float4 w1 = *(const float4*)(f_w + 128 + f0);
            float4 w2 = *(const float4*)(f_w + 256 + f0);
            float4 fb = *(const float4*)(f_b + f0);
            u16x4 av, bv;
#pragma unroll
            for (int j = 0; j < 4; ++j) {
                float ww0 = ((const float*)&w0)[j];
                float ww1 = ((const float*)&w1)[j];
                float ww2 = ((const float*)&w2)[j];
                float pw = p0 * ww0 + p1 * ww1 + p2 * ww2;
                float dw = d0 * ww0 + d1 * ww1 + d2 * ww2;
                av[j] = f2b(acca[nt][j] + pw);
                bv[j] = f2b(((const float*)&fb)[j] + dw - pw);
            }
            *(u16x4*)(A2h + (size_t)node * 128 + f0) = av;
            *(u16x4*)(Bvh + (size_t)node * 128 + f0) = bv;
        }
    }

    // histogram chunk (independent work, hides tail)
    int base = blockIdx.x * echunk;
    int end  = base + echunk; if (end > E) end = E;
    for (int i = base + tid; i < end; i += TPB)
        atomicAdd(&counts[ei[E + i]], 1);
}

// ---------------------------------------------------------------------------
// hierarchical exclusive scan of counts -> offs, cursor
// ---------------------------------------------------------------------------
__global__ __launch_bounds__(TPB) void scan1_kernel(
    const int* __restrict__ counts, int* __restrict__ partial)
{
    int tid = threadIdx.x;
    int4 v = *(const int4*)(counts + (size_t)blockIdx.x * 1024 + tid * 4);
    int s = v.x + v.y + v.z + v.w;
#pragma unroll
    for (int m = 1; m < 64; m <<= 1) s += __shfl_xor(s, m);
    __shared__ int ws[4];
    if ((tid & 63) == 0) ws[tid >> 6] = s;
    __syncthreads();
    if (tid == 0) partial[blockIdx.x] = ws[0] + ws[1] + ws[2] + ws[3];
}

__global__ __launch_bounds__(64) void scan2_kernel(
    int* __restrict__ partial, int* __restrict__ offs, int nblk, int M)
{
    int tid = threadIdx.x;
    int v = (tid < nblk) ? partial[tid] : 0;
    int s = v;
#pragma unroll
    for (int d = 1; d < 64; d <<= 1) {
        int t = __shfl_up(s, d);
        if (tid >= d) s += t;
    }
    if (tid < nblk) partial[tid] = s - v;   // exclusive
    if (tid == 63) offs[M] = s;             // total = E
}

__global__ __launch_bounds__(TPB) void scan3_kernel(
    const int* __restrict__ counts, const int* __restrict__ partial,
    int* __restrict__ offs, int* __restrict__ cursor, int M)
{
    int tid = threadIdx.x;
    int base = blockIdx.x * 1024 + tid * 4;
    int4 v = *(const int4*)(counts + base);
    int s = v.x + v.y + v.z + v.w;
    int incl = s;
#pragma unroll
    for (int d = 1; d < 64; d <<= 1) {
        int t = __shfl_up(incl, d);
        if ((tid & 63) >= d) incl += t;
    }
    __shared__ int ws[4];
    if ((tid & 63) == 63) ws[tid >> 6] = incl;
    __syncthreads();
    int wp = 0;
#pragma unroll
    for (int w = 0; w < 4; ++w) wp += (w < (tid >> 6)) ? ws[w] : 0;
    int run = partial[blockIdx.x] + wp + incl - s;
    int vv[4] = {v.x, v.y, v.z, v.w};
#pragma unroll
    for (int i = 0; i < 4; ++i) {
        if (base + i < M) { offs[base + i] = run; cursor[base + i] = run; }
        run += vv[i];
    }
}

__global__ __launch_bounds__(TPB) void scatter_kernel(
    const int* __restrict__ ei, int* __restrict__ cursor,
    int* __restrict__ ssrc, int E)
{
    int e = blockIdx.x * TPB + threadIdx.x;
    if (e >= E) return;
    int d = ei[E + e];
    int p = atomicAdd(&cursor[d], 1);
    ssrc[p] = ei[e];
}

// ---------------------------------------------------------------------------
// segmented reduce: ONE WAVE PER ROW (max TLP for the latency-bound gather),
// lane owns 2 cols, unroll-4, bf16 output.
// ---------------------------------------------------------------------------
__global__ __launch_bounds__(TPB) void reduce_kernel(
    const int* __restrict__ offs, const int* __restrict__ ssrc,
    const ushort* __restrict__ A2h, const ushort* __restrict__ Bvh,
    ushort* __restrict__ aggr, int M)
{
    int row = blockIdx.x * 4 + (threadIdx.x >> 6);
    if (row >= M) return;
    int lane = threadIdx.x & 63;
    int c = lane * 2;
    uint bu = *(const uint*)(Bvh + (size_t)row * 128 + c);
    float b0 = b2f_lo(bu), b1 = b2f_hi(bu);
    float a0 = 0.f, a1 = 0.f;
    int k  = offs[row];
    int k1 = offs[row + 1];
    for (; k + 3 < k1; k += 4) {
        int s0 = ssrc[k], s1 = ssrc[k + 1];
        int s2 = ssrc[k + 2], s3 = ssrc[k + 3];
        uint u0 = *(const uint*)(A2h + (size_t)s0 * 128 + c);
        uint u1 = *(const uint*)(A2h + (size_t)s1 * 128 + c);
        uint u2 = *(const uint*)(A2h + (size_t)s2 * 128 + c);
        uint u3 = *(const uint*)(A2h + (size_t)s3 * 128 + c);
        a0 += fmaxf(b2f_lo(u0) + b0, 0.f) + fmaxf(b2f_lo(u1) + b0, 0.f)
            + fmaxf(b2f_lo(u2) + b0, 0.f) + fmaxf(b2f_lo(u3) + b0, 0.f);
        a1 += fmaxf(b2f_hi(u0) + b1, 0.f) + fmaxf(b2f_hi(u1) + b1, 0.f)
            + fmaxf(b2f_hi(u2) + b1, 0.f) + fmaxf(b2f_hi(u3) + b1, 0.f);
    }
    for (; k < k1; ++k) {
        uint u0 = *(const uint*)(A2h + (size_t)ssrc[k] * 128 + c);
        a0 += fmaxf(b2f_lo(u0) + b0, 0.f);
        a1 += fmaxf(b2f_hi(u0) + b1, 0.f);
    }
    *(uint*)(aggr + (size_t)row * 128 + c) = (uint)f2b(a0) | ((uint)f2b(a1) << 16);
}

// ---------------------------------------------------------------------------
// post: out = relu(aggr@g_w1+g_b1)@g_w2 + g_b2 + x  via swapped MFMA.
// G1/G2 staged in one 32 KB LDS buffer (sequentially); hidden2 bounces
// through wave-private LDS.
// ---------------------------------------------------------------------------
__global__ __launch_bounds__(TPB) void post_kernel(
    const float* __restrict__ x, const ushort* __restrict__ aggr,
    const short* __restrict__ G1pk, const float* __restrict__ g_b1,
    const short* __restrict__ G2pk, const float* __restrict__ g_b2,
    float* __restrict__ out, int M)
{
    __shared__ short glds[16384];        // 32 KB staged weight
    __shared__ short bounce[4 * 16 * LPAD];
    const int tid  = threadIdx.x;
    const int lane = tid & 63;
    const int wave = tid >> 6;
    const int kg   = lane >> 4;
    short* ws = bounce + wave * 16 * LPAD;

    const int node = blockIdx.x * 64 + wave * 16 + (lane & 15);
    const int nc   = node < M ? node : M - 1;

    // B-fragments of aggr^T: direct 16B global loads (issue before staging)
    frag_ab ab[4];
#pragma unroll
    for (int ks = 0; ks < 4; ++ks)
        ab[ks] = *(const frag_ab*)(aggr + (size_t)nc * 128 + ks * 32 + kg * 8);

    // stage G1 (2048 int4s)
#pragma unroll
    for (int i = 0; i < 8; ++i) {
        int id = i * TPB + tid;
        *(int4*)(glds + (size_t)id * 8) = *(const int4*)(G1pk + (size_t)id * 8);
    }
    __syncthreads();

    // GEMM1: hidden2^T
    f32x4 h2[8];
#pragma unroll
    for (int nt = 0; nt < 8; ++nt) h2[nt] = (f32x4)0.f;
#pragma unroll
    for (int ks = 0; ks < 4; ++ks) {
#pragma unroll
        for (int nt = 0; nt < 8; ++nt) {
            frag_ab g = *(const frag_ab*)(glds + (((nt * 4 + ks) * 64 + lane) << 3));
            h2[nt] = __builtin_amdgcn_mfma_f32_16x16x32_bf16(g, ab[ks], h2[nt], 0, 0, 0);
        }
    }
    // relu+bias -> bf16 -> wave-private LDS
#pragma unroll
    for (int nt = 0; nt < 8; ++nt) {
        int f0 = nt * 16 + kg * 4;
        float4 gb = *(const float4*)(g_b1 + f0);
        u16x4 hv;
#pragma unroll
        for (int j = 0; j < 4; ++j)
            hv[j] = f2b(fmaxf(h2[nt][j] + ((const float*)&gb)[j], 0.f));
        *(u16x4*)(ws + (lane & 15) * LPAD + f0) = hv;
    }
    __syncthreads();   // all waves done reading G1

    // stage G2 over the same buffer
#pragma unroll
    for (int i = 0; i < 8; ++i) {
        int id = i * TPB + tid;
        *(int4*)(glds + (size_t)id * 8) = *(const int4*)(G2pk + (size_t)id * 8);
    }
    __syncthreads();

    // GEMM2: out^T
    f32x4 o[8];
#pragma unroll
    for (int nt = 0; nt < 8; ++nt) o[nt] = (f32x4)0.f;
#pragma unroll
    for (int ks = 0; ks < 4; ++ks) {
        frag_ab bfr = *(const frag_ab*)(ws + (lane & 15) * LPAD + ks * 32 + kg * 8);
#pragma unroll
        for (int nt = 0; nt < 8; ++nt) {
            frag_ab g = *(const frag_ab*)(glds + (((nt * 4 + ks) * 64 + lane) << 3));
            o[nt] = __builtin_amdgcn_mfma_f32_16x16x32_bf16(g, bfr, o[nt], 0, 0, 0);
        }
    }

    if (node < M) {
#pragma unroll
        for (int nt = 0; nt < 8; ++nt) {
            int f0 = nt * 16 + kg * 4;
            float4 xv = *(const float4*)(x + (size_t)node * 128 + f0);
            float4 gb = *(const float4*)(g_b2 + f0);
            float4 ov;
            ov.x = o[nt][0] + gb.x + xv.x;
            ov.y = o[nt][1] + gb.y + xv.y;
            ov.z = o[nt][2] + gb.z + xv.z;
            ov.w = o[nt][3] + gb.w + xv.w;
            *(float4*)(out + (size_t)node * 128 + f0) = ov;
        }
    }
}

extern "C" void kernel_launch(void* const* d_in, const int* in_sizes, int n_in,
                              void* d_out, int out_size, void* d_ws, size_t ws_size,
                              hipStream_t stream)
{
    const float* x    = (const float*)d_in[0];
    const float* pos  = (const float*)d_in[1];
    const int*   ei   = (const int*)d_in[2];
    const float* h_w1 = (const float*)d_in[3];
    const float* h_b1 = (const float*)d_in[4];
    const float* h_w2 = (const float*)d_in[5];
    const float* h_b2 = (const float*)d_in[6];
    const float* f_w  = (const float*)d_in[7];
    const float* f_b  = (const float*)d_in[8];
    const float* g_w1 = (const float*)d_in[9];
    const float* g_b1 = (const float*)d_in[10];
    const float* g_w2 = (const float*)d_in[11];
    const float* g_b2 = (const float*)d_in[12];

    const int M = in_sizes[1] / 3;       // 50000
    const int E = in_sizes[2] / 2;       // 600000
    const int nb = (M + 63) / 64;        // 782
    const int nblk = (M + 1023) / 1024;  // 49
    const int Mpad = nblk * 1024;
    const int echunk = (E + nb - 1) / nb;

    ushort* A2h  = (ushort*)d_ws;                          // [M][128] bf16
    ushort* Bvh  = A2h + (size_t)M * 128;                  // [M][128] bf16
    ushort* aggr = Bvh + (size_t)M * 128;                  // [M][128] bf16
    short* W1pk  = (short*)(aggr + (size_t)M * 128);       // 16384 each, W1|Wf contiguous
    short* Wfpk  = W1pk + 16384;
    short* G1pk  = Wfpk + 16384;
    short* G2pk  = G1pk + 16384;
    int* counts  = (int*)(G2pk + 16384);                   // [Mpad]
    int* partial = counts + Mpad;                          // [64]
    int* offs    = partial + 64;                           // [M+1]
    int* cursor  = offs + (M + 1);                         // [M]
    int* ssrc    = cursor + M;                             // [E]
    float* out   = (float*)d_out;

    hipMemsetAsync(counts, 0, (size_t)Mpad * sizeof(int), stream);
    pack_kernel<<<dim3(8, 4), TPB, 0, stream>>>(h_w1, f_w, g_w1, g_w2,
                                                W1pk, Wfpk, G1pk, G2pk);
    prehist_kernel<<<nb, TPB, 0, stream>>>(x, pos, W1pk, h_b1, h_w2, h_b2,
                                           f_w, f_b, A2h, Bvh,
                                           ei, counts, M, E, echunk);
    scan1_kernel<<<nblk, TPB, 0, stream>>>(counts, partial);
    scan2_kernel<<<1, 64, 0, stream>>>(partial, offs, nblk, M);
    scan3_kernel<<<nblk, TPB, 0, stream>>>(counts, partial, offs, cursor, M);
    scatter_kernel<<<(E + TPB - 1) / TPB, TPB, 0, stream>>>(ei, cursor, ssrc, E);
    reduce_kernel<<<(M + 3) / 4, TPB, 0, stream>>>(offs, ssrc, A2h, Bvh, aggr, M);
    post_kernel<<<nb, TPB, 0, stream>>>(x, aggr, G1pk, g_b1, G2pk, g_b2, out, M);
}